// Round 1
// baseline (1953.475 us; speedup 1.0000x reference)
//
#include <hip/hip_runtime.h>
#include <cstddef>

static constexpr int CB = 64;    // batch
static constexpr int CN = 512;   // nodes
static constexpr int CD = 256;   // node model dim
static constexpr int CE = 128;   // edge model dim
static constexpr int CIT = 20;   // sinkhorn iterations

typedef _Float16 half_t;
typedef __attribute__((ext_vector_type(8))) _Float16 v8h;
typedef __attribute__((ext_vector_type(4))) _Float16 v4h;
typedef __attribute__((ext_vector_type(4))) float v4f;

// ---------------------------------------------------------------------------
// k0: block 0 = mask layout detect; block 1 = zero the sync counters (only
// ~21.5 KB now — the 10.5 MB payload preclear is gone, payload readiness is
// signalled by release-counters instead of sign sentinels); blocks 2..9 =
// W_a -> fp16 B-fragments (w_aff folded); 10..17 = W_b.
// flag: 0=int32, 1=uint8(bool), 2=float32, 3=int64
// ---------------------------------------------------------------------------
__global__ __launch_bounds__(512) void k0_init(
    const void* __restrict__ mask, int* __restrict__ flag,
    const float* __restrict__ W_a, const float* __restrict__ W_b,
    const float* __restrict__ w_aff,
    half_t* __restrict__ WaF, half_t* __restrict__ WbF,
    float4* __restrict__ clearp, int nclear4) {
  const int tid = threadIdx.x;
  const int blk = blockIdx.x;
  if (blk == 1) {
    for (int idx = tid; idx < nclear4; idx += 512)
      clearp[idx] = make_float4(0.0f, 0.0f, 0.0f, 0.0f);
    return;
  }
  if (blk >= 2) {
    const bool is_a = (blk < 10);
    const float* W = is_a ? W_a : W_b;
    half_t* WF = is_a ? WaF : WbF;
    const int e = (blk - (is_a ? 2 : 10)) * 512 + tid;   // 0..4095
    const int fB = e >> 6, lane = e & 63;
    const int nn = fB >> 3, kf = fB & 7;
    const int col = nn * 16 + (lane & 15);
    const int q = lane >> 4;
    const float scale = is_a ? w_aff[col] : 1.0f;
    v8h hv;
#pragma unroll
    for (int j = 0; j < 8; ++j) {
      const int k = kf * 32 + q * 8 + j;
      hv[j] = (half_t)(W[(size_t)k * CE + col] * scale);
    }
    *(v8h*)&WF[(size_t)e * 8] = hv;
    return;
  }
  // blk == 0: mask dtype detection over first 32768 bytes
  __shared__ int cnt[5];
  if (tid < 5) cnt[tid] = 0;
  __syncthreads();
  const unsigned char* p = (const unsigned char*)mask;
  int l0 = 0, l1 = 0, l2 = 0, l3 = 0, l4 = 0;
  const int base = tid * 64;
  for (int k = 0; k < 64; ++k) {
    const int off = base + k;
    if (p[off]) {
      const int m4 = off & 3;
      if (m4 == 1) l1++;
      else if (m4 == 2) l2++;
      else if (m4 == 3) l3++;
      else if ((off & 7) == 4) l4++;
      else l0++;
    }
  }
  if (l0) atomicAdd(&cnt[0], 1);
  if (l1) atomicAdd(&cnt[1], 1);
  if (l2) atomicAdd(&cnt[2], 1);
  if (l3) atomicAdd(&cnt[3], 1);
  if (l4) atomicAdd(&cnt[4], 1);
  __syncthreads();
  if (tid == 0) {
    int f;
    if (cnt[1]) f = 1;
    else if (cnt[2] || cnt[3]) f = 2;
    else if (cnt[4]) f = 0;
    else if (cnt[0]) f = 3;
    else f = 1;
    *flag = f;
  }
}

// ---------------------------------------------------------------------------
// prep_both (validated R7/R8): ONE dispatch for both prep GEMMs. Blocks
// 0..511 = A-path (x = out_emb + pos, W = WaF w/ w_aff folded); 512..1023 =
// B-path (x = mask ? pad : in_emb, W = WbF). out fp16 row-major, K=256.
// ---------------------------------------------------------------------------
__global__ __launch_bounds__(256) void prep_both(
    const float* __restrict__ out_emb, const float* __restrict__ pos,
    const float* __restrict__ in_emb, const float* __restrict__ pad,
    const void* __restrict__ maskp, const int* __restrict__ flagp,
    const half_t* __restrict__ WaF, const half_t* __restrict__ WbF,
    half_t* __restrict__ A_h, half_t* __restrict__ Bm_h) {
  __shared__ half_t Xs[64][264];   // 33.8 KB
  const int tid = threadIdx.x;
  const int wv = tid >> 6, ln = tid & 63;
  const bool isA = blockIdx.x < 512;
  const int row0 = (isA ? blockIdx.x : blockIdx.x - 512) * 64;
  const float* X = isA ? out_emb : in_emb;
  const float* extra = isA ? pos : pad;
  const half_t* Wfrag = isA ? WaF : WbF;
  half_t* out = isA ? A_h : Bm_h;
  const int flag = isA ? 0 : *flagp;

#pragma unroll 4
  for (int it = 0; it < 16; ++it) {
    const int r = it * 4 + wv;
    const int row = row0 + r;
    const int c = ln * 4;
    float4 x4;
    if (isA) {
      x4 = *(const float4*)&X[(size_t)row * CD + c];
      const int i = row & (CN - 1);
      const float4 p4 = *(const float4*)&extra[(size_t)i * CD + c];
      x4.x += p4.x; x4.y += p4.y; x4.z += p4.z; x4.w += p4.w;
    } else {
      bool m;
      if (flag == 1)      m = ((const unsigned char*)maskp)[row] != 0;
      else if (flag == 2) m = ((const float*)maskp)[row] != 0.0f;
      else if (flag == 3) m = ((const long long*)maskp)[row] != 0;
      else                m = ((const int*)maskp)[row] != 0;
      if (m) x4 = *(const float4*)&extra[c];
      else   x4 = *(const float4*)&X[(size_t)row * CD + c];
    }
    v4h hv;
    hv[0] = (half_t)x4.x; hv[1] = (half_t)x4.y;
    hv[2] = (half_t)x4.z; hv[3] = (half_t)x4.w;
    *(v4h*)&Xs[r][c] = hv;
  }
  __syncthreads();

  const int q = ln >> 4, l = ln & 15;
  v8h af[8];
#pragma unroll
  for (int kf = 0; kf < 8; ++kf)
    af[kf] = *(v8h*)&Xs[wv * 16 + l][kf * 32 + q * 8];
  v4f acc[8] = {};
#pragma unroll
  for (int nn = 0; nn < 8; ++nn) {
    v8h bf[8];
#pragma unroll
    for (int kf = 0; kf < 8; ++kf)
      bf[kf] = *(const v8h*)&Wfrag[(size_t)((nn * 8 + kf) * 64 + ln) * 8];
#pragma unroll
    for (int kf = 0; kf < 8; ++kf)
      acc[nn] = __builtin_amdgcn_mfma_f32_16x16x32_f16(af[kf], bf[kf], acc[nn], 0, 0, 0);
  }
#pragma unroll
  for (int nn = 0; nn < 8; ++nn)
#pragma unroll
    for (int g = 0; g < 4; ++g) {
      const int row = row0 + wv * 16 + q * 4 + g;
      out[(size_t)row * CE + nn * 16 + l] = (half_t)acc[nn][g];
    }
}

// ---------------------------------------------------------------------------
// fused_reg: block = (batch b, 128-row slab), 512 thr = 8 waves, grid 256 =
// 1 block/CU. E slab in registers TWICE as fp16 (eh = C-layout / B-operand,
// ehT = transposed twin). Sinkhorn passes are MFMAs; this revision packs the
// two weight vectors into A-rows 0/1 of a SINGLE mfma (row0 = w1/u,
// row1 = w2/uri), halving pass1+pass2 MFMA count and LDS reads.
//
// NEW exchange protocol (this round's bet): payloads are PLAIN coalesced
// stores/loads; readiness is a per-(t,b,slab) release-counter. Per wave:
//   plain Q stores -> __threadfence() -> lane0 release fetch_add(ctr).
// Peers spin on the 3 remote ctrs with 3 relaxed 4B loads per WAVE (was a
// 1536-wide per-thread payload spin), then __threadfence() and read payloads
// once with plain coalesced loads. This removes the per-thread agent-scope
// atomic-store storm (each 4B store = its own ~32B LLC transaction; the
// source of the ~70 MB WRITE_SIZE inflation and the publish-drain latency).
// ---------------------------------------------------------------------------
__global__ __launch_bounds__(512, 2) void fused_reg(
    const half_t* __restrict__ A_h, const half_t* __restrict__ B_h,
    const float* __restrict__ baff, float* __restrict__ P,
    float* __restrict__ partInit, float* __restrict__ partIter,
    unsigned int* __restrict__ ctrInit, unsigned int* __restrict__ ctrIter) {
  __shared__ float comb2[8][512][2];     // 32 KB, [wave][col][s1|s2]
  __shared__ float2 w12[512];            // {0.5*v*csinv, v} fp32 (finalize)
  __shared__ half_t w1h[512];            // fp16 weights for pass1 fragments
  __shared__ half_t w2h[512];

  const int tid = threadIdx.x;
  const int wv = tid >> 6, ln = tid & 63;
  const int q = ln >> 4, l = ln & 15;
  const int b = blockIdx.x & 63;
  const int slab = blockIdx.x >> 6;
  const int i0 = slab * 128;
  const float bbs = *baff - 2.7725887f;   // fold 2^-4 scale into exp

  int rs3[3];   // the 3 remote slabs (static-indexed only)
  {
    int k = 0;
#pragma unroll
    for (int sl = 0; sl < 4; ++sl)
      if (sl != slab) rs3[k++] = sl;
  }
  // remote slab polled by lane ln (<3): arithmetic, no dynamic array index
  const int rsl = (ln < 3) ? (ln + (ln >= slab ? 1 : 0)) : 0;

  // ---- GEMM: E and E^T tiles, fp16 MFMA, K=128 ----
  v8h af[4];
  {
    const half_t* Arow = &A_h[((size_t)b * CN + i0 + wv * 16 + l) * CE];
#pragma unroll
    for (int ki = 0; ki < 4; ++ki)
      af[ki] = *(const v8h*)&Arow[ki * 32 + q * 8];
  }
  v4h eh[32];    // E[row = wv*16 + q*4+g][col = ct*16 + l]
  v4h ehT[32];   // E[row = wv*16 + l][col = ct*16 + q*4+g]
  const half_t* Bbase = &B_h[(size_t)b * CN * CE];
#pragma unroll
  for (int ct = 0; ct < 32; ++ct) {
    v8h bf[4];
    const half_t* Brow = &Bbase[(size_t)(ct * 16 + l) * CE];
#pragma unroll
    for (int ki = 0; ki < 4; ++ki)
      bf[ki] = *(const v8h*)&Brow[ki * 32 + q * 8];
    v4f acc = {}, accT = {};
#pragma unroll
    for (int ki = 0; ki < 4; ++ki) {
      acc  = __builtin_amdgcn_mfma_f32_16x16x32_f16(af[ki], bf[ki], acc,  0, 0, 0);
      accT = __builtin_amdgcn_mfma_f32_16x16x32_f16(bf[ki], af[ki], accT, 0, 0, 0);
    }
#pragma unroll
    for (int g = 0; g < 4; ++g) {
      eh[ct][g]  = (half_t)__expf(acc[g]  + bbs);
      ehT[ct][g] = (half_t)__expf(accT[g] + bbs);
    }
  }

  // ---- init sums via MFMA (ones fragment) ----
  v4h ones;
  ones[0] = (half_t)1.0f; ones[1] = (half_t)1.0f;
  ones[2] = (half_t)1.0f; ones[3] = (half_t)1.0f;
  v4f rowacc0 = {}, rowacc1 = {};
#pragma unroll
  for (int ct = 0; ct < 32; ct += 2) {
    const v4f c0 = __builtin_amdgcn_mfma_f32_16x16x16f16(ones, eh[ct], (v4f){}, 0, 0, 0);
    const v4f c1 = __builtin_amdgcn_mfma_f32_16x16x16f16(ones, eh[ct + 1], (v4f){}, 0, 0, 0);
    if (ln < 16) {
      comb2[wv][ct * 16 + ln][0] = c0[0];
      comb2[wv][(ct + 1) * 16 + ln][0] = c1[0];
    }
    rowacc0 = __builtin_amdgcn_mfma_f32_16x16x16f16(ones, ehT[ct],     rowacc0, 0, 0, 0);
    rowacc1 = __builtin_amdgcn_mfma_f32_16x16x16f16(ones, ehT[ct + 1], rowacc1, 0, 0, 0);
  }
  const float rowtot = rowacc0[0] + rowacc1[0];
  float rv[4];   // 1/rowsum for this lane's 4 rows (q*4+g)
#pragma unroll
  for (int g = 0; g < 4; ++g)
    rv[g] = 1.0f / __shfl(rowtot, q * 4 + g);
  __syncthreads();

  // ---- init exchange: plain payload stores + release-counter ----
  float ci0;    // 1/colsum for column tid (register-carried; no LDS copy)
  {
    float S = 0.0f;
#pragma unroll
    for (int w = 0; w < 8; ++w) S += comb2[w][tid][0];
    partInit[(((size_t)b * 4 + slab) * 512) + tid] = S;   // plain, coalesced
    __threadfence();                                      // drain + L2 wb
    unsigned int* cip = &ctrInit[b * 4];
    if (ln == 0)
      __hip_atomic_fetch_add(&cip[slab], 1u, __ATOMIC_RELEASE,
                             __HIP_MEMORY_SCOPE_AGENT);
    while (true) {
      unsigned int f = 8u;
      if (ln < 3)
        f = __hip_atomic_load(&cip[rsl], __ATOMIC_RELAXED,
                              __HIP_MEMORY_SCOPE_AGENT);
      if (__all(f >= 8u)) break;
      __builtin_amdgcn_s_sleep(1);
    }
    __threadfence();                                      // L2 inv before plain reads
    const float* pb = &partInit[(size_t)b * 4 * 512];
    const float v0 = pb[rs3[0] * 512 + tid];
    const float v1 = pb[rs3[1] * 512 + tid];
    const float v2 = pb[rs3[2] * 512 + tid];
    const float T = S + v0 + v1 + v2;
    ci0 = 1.0f / T;
    w1h[tid] = (half_t)(0.5f * ci0);
    w2h[tid] = (half_t)1.0f;
  }

  // ---- 20 sinkhorn iterations (packed MFMA passes) ----
  // pass1 A-operand: row0 = w1, row1 = w2 (lane with (ln&15)==1 carries w2).
  const half_t* wbase = (l == 1) ? w2h : w1h;
  float u_[4], uri[4];
  float vv = 1.0f;
  for (int t = 0; t < CIT; ++t) {
    __syncthreads();   // w1h/w2h ready
    // pass 1: row dots via E^T tiles; ONE mfma per ct (rows 0/1 = w1/w2),
    // two interleaved accumulators to shorten the dependent chain
    v4f Pe = {}, Po = {};
#pragma unroll
    for (int ct = 0; ct < 32; ct += 2) {
      const v4h wf0 = *(const v4h*)&wbase[ct * 16 + q * 4];
      const v4h wf1 = *(const v4h*)&wbase[(ct + 1) * 16 + q * 4];
      Pe = __builtin_amdgcn_mfma_f32_16x16x16f16(wf0, ehT[ct],     Pe, 0, 0, 0);
      Po = __builtin_amdgcn_mfma_f32_16x16x16f16(wf1, ehT[ct + 1], Po, 0, 0, 0);
    }
    const float Prow1 = Pe[0] + Po[0];   // w1-weighted row dot (C row 0)
    const float Prow2 = Pe[1] + Po[1];   // w2-weighted row dot (C row 1)
    // redistribute p[row l&15] -> this lane's rows q*4+g; compute u
    v4h u_h, uri_h;
#pragma unroll
    for (int g = 0; g < 4; ++g) {
      const float p1 = __shfl(Prow1, q * 4 + g);
      const float p2 = __shfl(Prow2, q * 4 + g);
      u_[g] = 1.0f / (p1 + 0.5f * rv[g] * p2);
      uri[g] = u_[g] * rv[g];
      u_h[g] = (half_t)u_[g];
      uri_h[g] = (half_t)uri[g];
    }
    // pass 2: column partials via E tiles; rows 0/1 of A = u/uri packed
    const v4h a2 = (l == 1) ? uri_h : u_h;
#pragma unroll
    for (int ct = 0; ct < 32; ++ct) {
      const v4f s = __builtin_amdgcn_mfma_f32_16x16x16f16(a2, eh[ct], (v4f){}, 0, 0, 0);
      if (ln < 16)
        *(float2*)&comb2[wv][ct * 16 + ln][0] = make_float2(s[0], s[1]);
    }
    __syncthreads();
    // cross-wave reduce + pre-combined publish: Q = 0.5*(ci*S1 + S2)
    float S1 = 0.0f, S2 = 0.0f;
#pragma unroll
    for (int w = 0; w < 8; ++w) {
      const float2 c2v = *(const float2*)&comb2[w][tid][0];
      S1 += c2v.x;
      S2 += c2v.y;
    }
    const float Q = 0.5f * fmaf(ci0, S1, S2);
    float* pr = &partIter[(((size_t)t * 64 + b) * 4) * 512];
    pr[slab * 512 + tid] = Q;                              // plain, coalesced
    __threadfence();                                       // drain + L2 wb
    unsigned int* ct_ = &ctrIter[((size_t)t * 64 + b) * 4];
    if (ln == 0)
      __hip_atomic_fetch_add(&ct_[slab], 1u, __ATOMIC_RELEASE,
                             __HIP_MEMORY_SCOPE_AGENT);
    while (true) {
      unsigned int f = 8u;
      if (ln < 3)
        f = __hip_atomic_load(&ct_[rsl], __ATOMIC_RELAXED,
                              __HIP_MEMORY_SCOPE_AGENT);
      if (__all(f >= 8u)) break;
      __builtin_amdgcn_s_sleep(1);
    }
    __threadfence();                                       // L2 inv before plain reads
    const float v0 = pr[rs3[0] * 512 + tid];
    const float v1 = pr[rs3[1] * 512 + tid];
    const float v2 = pr[rs3[2] * 512 + tid];
    vv = 1.0f / (Q + v0 + v1 + v2);
    w1h[tid] = (half_t)(0.5f * vv * ci0);
    w2h[tid] = (half_t)vv;
  }

  // ---- finalize: P = E * u_i * v_j * (0.5*csinv_j + 0.5*rinv_i) ----
  w12[tid] = make_float2(0.5f * vv * ci0, vv);
  __syncthreads();
  float* Pb = &P[((size_t)b * CN + i0 + wv * 16 + q * 4) * CN];
#pragma unroll
  for (int ct = 0; ct < 32; ++ct) {
    const float2 w = w12[ct * 16 + l];
    const float c1 = w.x;
    const float c2 = 0.5f * w.y;
#pragma unroll
    for (int g = 0; g < 4; ++g) {
      const float e = (float)eh[ct][g];
      Pb[(size_t)g * CN + ct * 16 + l] = e * fmaf(u_[g], c1, uri[g] * c2);
    }
  }
}

// ---------------------------------------------------------------------------
extern "C" void kernel_launch(void* const* d_in, const int* in_sizes, int n_in,
                              void* d_out, int out_size, void* d_ws, size_t ws_size,
                              hipStream_t stream) {
  const float* in_emb  = (const float*)d_in[0];
  const void*  mask    = d_in[1];
  const float* out_emb = (const float*)d_in[2];
  const float* pad     = (const float*)d_in[3];
  const float* pos     = (const float*)d_in[4];
  const float* W_a     = (const float*)d_in[5];
  const float* W_b     = (const float*)d_in[6];
  const float* w_aff   = (const float*)d_in[7];
  const float* b_aff   = (const float*)d_in[8];
  float* P = (float*)d_out;

  char* ws = (char*)d_ws;
  const size_t MB = 1024 * 1024;
  half_t* A_h  = (half_t*)ws;                              // 8 MB
  half_t* Bm_h = (half_t*)(ws + 8 * MB);                   // 8 MB
  int*    flag = (int*)(ws + 16 * MB);                     // 4 B
  half_t* WaF  = (half_t*)(ws + 16 * MB + 16384);          // 64 KB
  half_t* WbF  = (half_t*)(ws + 16 * MB + 16384 + 65536);  // 64 KB
  unsigned int* ctrInit = (unsigned int*)(ws + 16 * MB + 160 * 1024);  // 1 KB
  unsigned int* ctrIter = ctrInit + 256;                   // 20 KB (20*64*4)
  float* partInit = (float*)(ws + 16 * MB + 256 * 1024);   // 512 KB
  float* partIter = (float*)(ws + 16 * MB + 768 * 1024);   // 10 MB

  // sync counters to zero each launch: 64*4 init + 20*64*4 iter uints
  const int nclear4 = (64 * 4 * 4 + CIT * 64 * 4 * 4) / 16;   // 1344 float4

  k0_init<<<dim3(18), dim3(512), 0, stream>>>(
      mask, flag, W_a, W_b, w_aff, WaF, WbF, (float4*)ctrInit, nclear4);
  prep_both<<<dim3(1024), dim3(256), 0, stream>>>(
      out_emb, pos, in_emb, pad, mask, flag, WaF, WbF, A_h, Bm_h);
  fused_reg<<<dim3(256), dim3(512), 0, stream>>>(
      A_h, Bm_h, b_aff, P, partInit, partIter, ctrInit, ctrIter);
}

// Round 2
// 308.170 us; speedup vs baseline: 6.3390x; 6.3390x over previous
//
#include <hip/hip_runtime.h>
#include <cstddef>

static constexpr int CB = 64;    // batch
static constexpr int CN = 512;   // nodes
static constexpr int CD = 256;   // node model dim
static constexpr int CE = 128;   // edge model dim
static constexpr int CIT = 20;   // sinkhorn iterations

typedef _Float16 half_t;
typedef __attribute__((ext_vector_type(8))) _Float16 v8h;
typedef __attribute__((ext_vector_type(4))) _Float16 v4h;
typedef __attribute__((ext_vector_type(4))) float v4f;

// ---------------------------------------------------------------------------
// LLC-coherent 16B ops (same semantics class as relaxed agent atomics: bypass
// L1/L2 to the coherence point; NO fences, NO cache-maintenance ops — R1
// showed buffer_wbl2/buffer_inv storms from release/acquire cost ~90 µs/iter).
// Correctness: payload-as-flag sentinel (-1 precleared, strictly-positive
// payload); each 4B word flips monotonically once, reader accepts a float4
// only when all 4 words are positive, so 16B tearing is harmless.
// ---------------------------------------------------------------------------
__device__ __forceinline__ void llc_store4(v4f* p, v4f v) {
  asm volatile("global_store_dwordx4 %0, %1, off sc0 sc1"
               :: "v"(p), "v"(v) : "memory");
}
__device__ __forceinline__ void llc_load3x4(const v4f* p0, const v4f* p1,
                                            const v4f* p2,
                                            v4f& a, v4f& b, v4f& c) {
  asm volatile("global_load_dwordx4 %0, %3, off sc0 sc1\n\t"
               "global_load_dwordx4 %1, %4, off sc0 sc1\n\t"
               "global_load_dwordx4 %2, %5, off sc0 sc1\n\t"
               "s_waitcnt vmcnt(0)"
               : "=&v"(a), "=&v"(b), "=&v"(c)
               : "v"(p0), "v"(p1), "v"(p2)
               : "memory");
}

// ---------------------------------------------------------------------------
// k0: block 0 = mask layout detect; block 1 = idle; blocks 2..9 = W_a -> fp16
// B-fragments (w_aff folded); 10..17 = W_b; blocks >= 18 clear the dataflow
// slot region to -1.0f (sentinel). flag: 0=int32, 1=uint8, 2=float32, 3=int64
// ---------------------------------------------------------------------------
__global__ __launch_bounds__(512) void k0_init(
    const void* __restrict__ mask, int* __restrict__ flag,
    const float* __restrict__ W_a, const float* __restrict__ W_b,
    const float* __restrict__ w_aff,
    half_t* __restrict__ WaF, half_t* __restrict__ WbF,
    float4* __restrict__ clearp, int nclear4) {
  const int tid = threadIdx.x;
  const int blk = blockIdx.x;
  if (blk == 1) return;
  if (blk >= 18) {
    const int idx = (blk - 18) * 512 + tid;
    if (idx < nclear4)
      clearp[idx] = make_float4(-1.0f, -1.0f, -1.0f, -1.0f);
    return;
  }
  if (blk >= 2) {
    const bool is_a = (blk < 10);
    const float* W = is_a ? W_a : W_b;
    half_t* WF = is_a ? WaF : WbF;
    const int e = (blk - (is_a ? 2 : 10)) * 512 + tid;   // 0..4095
    const int fB = e >> 6, lane = e & 63;
    const int nn = fB >> 3, kf = fB & 7;
    const int col = nn * 16 + (lane & 15);
    const int q = lane >> 4;
    const float scale = is_a ? w_aff[col] : 1.0f;
    v8h hv;
#pragma unroll
    for (int j = 0; j < 8; ++j) {
      const int k = kf * 32 + q * 8 + j;
      hv[j] = (half_t)(W[(size_t)k * CE + col] * scale);
    }
    *(v8h*)&WF[(size_t)e * 8] = hv;
    return;
  }
  // blk == 0: mask dtype detection over first 32768 bytes
  __shared__ int cnt[5];
  if (tid < 5) cnt[tid] = 0;
  __syncthreads();
  const unsigned char* p = (const unsigned char*)mask;
  int l0 = 0, l1 = 0, l2 = 0, l3 = 0, l4 = 0;
  const int base = tid * 64;
  for (int k = 0; k < 64; ++k) {
    const int off = base + k;
    if (p[off]) {
      const int m4 = off & 3;
      if (m4 == 1) l1++;
      else if (m4 == 2) l2++;
      else if (m4 == 3) l3++;
      else if ((off & 7) == 4) l4++;
      else l0++;
    }
  }
  if (l0) atomicAdd(&cnt[0], 1);
  if (l1) atomicAdd(&cnt[1], 1);
  if (l2) atomicAdd(&cnt[2], 1);
  if (l3) atomicAdd(&cnt[3], 1);
  if (l4) atomicAdd(&cnt[4], 1);
  __syncthreads();
  if (tid == 0) {
    int f;
    if (cnt[1]) f = 1;
    else if (cnt[2] || cnt[3]) f = 2;
    else if (cnt[4]) f = 0;
    else if (cnt[0]) f = 3;
    else f = 1;
    *flag = f;
  }
}

// ---------------------------------------------------------------------------
// prep_both (validated R7/R8): ONE dispatch for both prep GEMMs. Blocks
// 0..511 = A-path (x = out_emb + pos, W = WaF w/ w_aff folded); 512..1023 =
// B-path (x = mask ? pad : in_emb, W = WbF). out fp16 row-major, K=256.
// ---------------------------------------------------------------------------
__global__ __launch_bounds__(256) void prep_both(
    const float* __restrict__ out_emb, const float* __restrict__ pos,
    const float* __restrict__ in_emb, const float* __restrict__ pad,
    const void* __restrict__ maskp, const int* __restrict__ flagp,
    const half_t* __restrict__ WaF, const half_t* __restrict__ WbF,
    half_t* __restrict__ A_h, half_t* __restrict__ Bm_h) {
  __shared__ half_t Xs[64][264];   // 33.8 KB
  const int tid = threadIdx.x;
  const int wv = tid >> 6, ln = tid & 63;
  const bool isA = blockIdx.x < 512;
  const int row0 = (isA ? blockIdx.x : blockIdx.x - 512) * 64;
  const float* X = isA ? out_emb : in_emb;
  const float* extra = isA ? pos : pad;
  const half_t* Wfrag = isA ? WaF : WbF;
  half_t* out = isA ? A_h : Bm_h;
  const int flag = isA ? 0 : *flagp;

#pragma unroll 4
  for (int it = 0; it < 16; ++it) {
    const int r = it * 4 + wv;
    const int row = row0 + r;
    const int c = ln * 4;
    float4 x4;
    if (isA) {
      x4 = *(const float4*)&X[(size_t)row * CD + c];
      const int i = row & (CN - 1);
      const float4 p4 = *(const float4*)&extra[(size_t)i * CD + c];
      x4.x += p4.x; x4.y += p4.y; x4.z += p4.z; x4.w += p4.w;
    } else {
      bool m;
      if (flag == 1)      m = ((const unsigned char*)maskp)[row] != 0;
      else if (flag == 2) m = ((const float*)maskp)[row] != 0.0f;
      else if (flag == 3) m = ((const long long*)maskp)[row] != 0;
      else                m = ((const int*)maskp)[row] != 0;
      if (m) x4 = *(const float4*)&extra[c];
      else   x4 = *(const float4*)&X[(size_t)row * CD + c];
    }
    v4h hv;
    hv[0] = (half_t)x4.x; hv[1] = (half_t)x4.y;
    hv[2] = (half_t)x4.z; hv[3] = (half_t)x4.w;
    *(v4h*)&Xs[r][c] = hv;
  }
  __syncthreads();

  const int q = ln >> 4, l = ln & 15;
  v8h af[8];
#pragma unroll
  for (int kf = 0; kf < 8; ++kf)
    af[kf] = *(v8h*)&Xs[wv * 16 + l][kf * 32 + q * 8];
  v4f acc[8] = {};
#pragma unroll
  for (int nn = 0; nn < 8; ++nn) {
    v8h bf[8];
#pragma unroll
    for (int kf = 0; kf < 8; ++kf)
      bf[kf] = *(const v8h*)&Wfrag[(size_t)((nn * 8 + kf) * 64 + ln) * 8];
#pragma unroll
    for (int kf = 0; kf < 8; ++kf)
      acc[nn] = __builtin_amdgcn_mfma_f32_16x16x32_f16(af[kf], bf[kf], acc[nn], 0, 0, 0);
  }
#pragma unroll
  for (int nn = 0; nn < 8; ++nn)
#pragma unroll
    for (int g = 0; g < 4; ++g) {
      const int row = row0 + wv * 16 + q * 4 + g;
      out[(size_t)row * CE + nn * 16 + l] = (half_t)acc[nn][g];
    }
}

// ---------------------------------------------------------------------------
// fused_reg: block = (batch b, 128-row slab), 512 thr = 8 waves, grid 256.
// E slab in registers TWICE as fp16 (eh = C-layout, ehT = transposed twin).
// Packed Sinkhorn passes (validated R1 math): A-rows 0/1 carry {w1,w2} /
// {u,uri}, ONE mfma per ct per pass (half the MFMA count of R0).
// Exchange: fence-free sentinel dataflow (validated R0 protocol) upgraded to
// 16B sc0sc1 vector ops on 128 threads (4x fewer LLC transactions).
// ---------------------------------------------------------------------------
__global__ __launch_bounds__(512, 2) void fused_reg(
    const half_t* __restrict__ A_h, const half_t* __restrict__ B_h,
    const float* __restrict__ baff, float* __restrict__ P,
    float* __restrict__ partInit, float* __restrict__ partIter) {
  __shared__ float comb2[8][512][2];           // 32 KB, [wave][col][s1|s2]
  __shared__ __align__(16) float2 w12[512];    // {0.5*v*csinv, v} fp32 (finalize)
  __shared__ __align__(16) float QsL[512];     // per-col publish staging
  __shared__ __align__(16) v4f csinv4[128];    // 1/colsum, 4 cols per slot
  __shared__ half_t w1h[512];                  // fp16 weights for pass1
  __shared__ half_t w2h[512];

  const int tid = threadIdx.x;
  const int wv = tid >> 6, ln = tid & 63;
  const int q = ln >> 4, l = ln & 15;
  const int b = blockIdx.x & 63;
  const int slab = blockIdx.x >> 6;
  const int i0 = slab * 128;
  const float bbs = *baff - 2.7725887f;   // fold 2^-4 scale into exp

  int rs3[3];   // the 3 remote slabs (static-indexed only)
  {
    int k = 0;
#pragma unroll
    for (int sl = 0; sl < 4; ++sl)
      if (sl != slab) rs3[k++] = sl;
  }

  // ---- GEMM: E and E^T tiles, fp16 MFMA, K=128 ----
  v8h af[4];
  {
    const half_t* Arow = &A_h[((size_t)b * CN + i0 + wv * 16 + l) * CE];
#pragma unroll
    for (int ki = 0; ki < 4; ++ki)
      af[ki] = *(const v8h*)&Arow[ki * 32 + q * 8];
  }
  v4h eh[32];    // E[row = wv*16 + q*4+g][col = ct*16 + l]
  v4h ehT[32];   // E[row = wv*16 + l][col = ct*16 + q*4+g]
  const half_t* Bbase = &B_h[(size_t)b * CN * CE];
#pragma unroll
  for (int ct = 0; ct < 32; ++ct) {
    v8h bf[4];
    const half_t* Brow = &Bbase[(size_t)(ct * 16 + l) * CE];
#pragma unroll
    for (int ki = 0; ki < 4; ++ki)
      bf[ki] = *(const v8h*)&Brow[ki * 32 + q * 8];
    v4f acc = {}, accT = {};
#pragma unroll
    for (int ki = 0; ki < 4; ++ki) {
      acc  = __builtin_amdgcn_mfma_f32_16x16x32_f16(af[ki], bf[ki], acc,  0, 0, 0);
      accT = __builtin_amdgcn_mfma_f32_16x16x32_f16(bf[ki], af[ki], accT, 0, 0, 0);
    }
#pragma unroll
    for (int g = 0; g < 4; ++g) {
      eh[ct][g]  = (half_t)__expf(acc[g]  + bbs);
      ehT[ct][g] = (half_t)__expf(accT[g] + bbs);
    }
  }

  // ---- init sums via MFMA (ones fragment) ----
  v4h ones;
  ones[0] = (half_t)1.0f; ones[1] = (half_t)1.0f;
  ones[2] = (half_t)1.0f; ones[3] = (half_t)1.0f;
  v4f rowacc0 = {}, rowacc1 = {};
#pragma unroll
  for (int ct = 0; ct < 32; ct += 2) {
    const v4f c0 = __builtin_amdgcn_mfma_f32_16x16x16f16(ones, eh[ct], (v4f){}, 0, 0, 0);
    const v4f c1 = __builtin_amdgcn_mfma_f32_16x16x16f16(ones, eh[ct + 1], (v4f){}, 0, 0, 0);
    if (ln < 16) {
      comb2[wv][ct * 16 + ln][0] = c0[0];
      comb2[wv][(ct + 1) * 16 + ln][0] = c1[0];
    }
    rowacc0 = __builtin_amdgcn_mfma_f32_16x16x16f16(ones, ehT[ct],     rowacc0, 0, 0, 0);
    rowacc1 = __builtin_amdgcn_mfma_f32_16x16x16f16(ones, ehT[ct + 1], rowacc1, 0, 0, 0);
  }
  const float rowtot = rowacc0[0] + rowacc1[0];
  float rv[4];   // 1/rowsum for this lane's 4 rows (q*4+g)
#pragma unroll
  for (int g = 0; g < 4; ++g)
    rv[g] = 1.0f / __shfl(rowtot, q * 4 + g);
  __syncthreads();

  // ---- init exchange: sentinel dataflow, 16B ops on 128 threads ----
  {
    float S = 0.0f;
#pragma unroll
    for (int w = 0; w < 8; ++w) S += comb2[w][tid][0];
    QsL[tid] = S;                 // colsum staging (strictly positive)
  }
  __syncthreads();
  if (tid < 128) {
    const v4f s4 = *(const v4f*)&QsL[tid * 4];
    v4f* pi4 = (v4f*)partInit + (size_t)b * 4 * 128;
    llc_store4(&pi4[slab * 128 + tid], s4);
    const v4f* q0 = &pi4[rs3[0] * 128 + tid];
    const v4f* q1 = &pi4[rs3[1] * 128 + tid];
    const v4f* q2 = &pi4[rs3[2] * 128 + tid];
    v4f r0, r1, r2;
    while (true) {
      llc_load3x4(q0, q1, q2, r0, r1, r2);
      if (r0[0] > 0.0f && r0[1] > 0.0f && r0[2] > 0.0f && r0[3] > 0.0f &&
          r1[0] > 0.0f && r1[1] > 0.0f && r1[2] > 0.0f && r1[3] > 0.0f &&
          r2[0] > 0.0f && r2[1] > 0.0f && r2[2] > 0.0f && r2[3] > 0.0f)
        break;
      __builtin_amdgcn_s_sleep(1);
    }
    const v4f T = s4 + r0 + r1 + r2;
    v4f ci;
    v4h w1v, w2v;
#pragma unroll
    for (int j = 0; j < 4; ++j) {
      ci[j] = 1.0f / T[j];
      w1v[j] = (half_t)(0.5f * ci[j]);
      w2v[j] = (half_t)1.0f;
    }
    csinv4[tid] = ci;
    *(v4h*)&w1h[tid * 4] = w1v;
    *(v4h*)&w2h[tid * 4] = w2v;
  }
  __syncthreads();
  const float ci0 = ((const float*)csinv4)[tid];   // 1/colsum for column tid

  // ---- 20 sinkhorn iterations (packed MFMA passes) ----
  const half_t* wbase = (l == 1) ? w2h : w1h;   // A-row 0 = w1, row 1 = w2
  float u_[4], uri[4];
  for (int t = 0; t < CIT; ++t) {
    __syncthreads();   // w1h/w2h ready
    // pass 1: row dots via E^T tiles; ONE mfma per ct (rows 0/1 = w1/w2)
    v4f Pe = {}, Po = {};
#pragma unroll
    for (int ct = 0; ct < 32; ct += 2) {
      const v4h wf0 = *(const v4h*)&wbase[ct * 16 + q * 4];
      const v4h wf1 = *(const v4h*)&wbase[(ct + 1) * 16 + q * 4];
      Pe = __builtin_amdgcn_mfma_f32_16x16x16f16(wf0, ehT[ct],     Pe, 0, 0, 0);
      Po = __builtin_amdgcn_mfma_f32_16x16x16f16(wf1, ehT[ct + 1], Po, 0, 0, 0);
    }
    const float Prow1 = Pe[0] + Po[0];   // w1-weighted row dot (C row 0)
    const float Prow2 = Pe[1] + Po[1];   // w2-weighted row dot (C row 1)
    // redistribute p[row l&15] -> this lane's rows q*4+g; compute u
    v4h u_h, uri_h;
#pragma unroll
    for (int g = 0; g < 4; ++g) {
      const float p1 = __shfl(Prow1, q * 4 + g);
      const float p2 = __shfl(Prow2, q * 4 + g);
      u_[g] = 1.0f / (p1 + 0.5f * rv[g] * p2);
      uri[g] = u_[g] * rv[g];
      u_h[g] = (half_t)u_[g];
      uri_h[g] = (half_t)uri[g];
    }
    // pass 2: column partials via E tiles; rows 0/1 of A = u/uri packed
    const v4h a2 = (l == 1) ? uri_h : u_h;
#pragma unroll
    for (int ct = 0; ct < 32; ++ct) {
      const v4f s = __builtin_amdgcn_mfma_f32_16x16x16f16(a2, eh[ct], (v4f){}, 0, 0, 0);
      if (ln < 16)
        *(float2*)&comb2[wv][ct * 16 + ln][0] = make_float2(s[0], s[1]);
    }
    __syncthreads();
    // cross-wave reduce (all 512 threads) + stage Q = 0.5*(ci*S1 + S2)
    {
      float S1 = 0.0f, S2 = 0.0f;
#pragma unroll
      for (int w = 0; w < 8; ++w) {
        const float2 c2v = *(const float2*)&comb2[w][tid][0];
        S1 += c2v.x;
        S2 += c2v.y;
      }
      QsL[tid] = 0.5f * fmaf(ci0, S1, S2);   // strictly positive
    }
    __syncthreads();
    // 128-thread 16B sentinel exchange + w update
    if (tid < 128) {
      const v4f Q4 = *(const v4f*)&QsL[tid * 4];
      v4f* pr4 = (v4f*)partIter + (((size_t)t * 64 + b) * 4) * 128;
      llc_store4(&pr4[slab * 128 + tid], Q4);
      const v4f* q0 = &pr4[rs3[0] * 128 + tid];
      const v4f* q1 = &pr4[rs3[1] * 128 + tid];
      const v4f* q2 = &pr4[rs3[2] * 128 + tid];
      v4f r0, r1, r2;
      while (true) {
        llc_load3x4(q0, q1, q2, r0, r1, r2);
        if (r0[0] > 0.0f && r0[1] > 0.0f && r0[2] > 0.0f && r0[3] > 0.0f &&
            r1[0] > 0.0f && r1[1] > 0.0f && r1[2] > 0.0f && r1[3] > 0.0f &&
            r2[0] > 0.0f && r2[1] > 0.0f && r2[2] > 0.0f && r2[3] > 0.0f)
          break;
        __builtin_amdgcn_s_sleep(1);
      }
      const v4f tot = Q4 + r0 + r1 + r2;
      const v4f ci = csinv4[tid];
      v4h w1v, w2v;
#pragma unroll
      for (int j = 0; j < 4; ++j) {
        const float vv = 1.0f / tot[j];
        w1v[j] = (half_t)(0.5f * vv * ci[j]);
        w2v[j] = (half_t)vv;
        if (t == CIT - 1)
          w12[tid * 4 + j] = make_float2(0.5f * vv * ci[j], vv);
      }
      *(v4h*)&w1h[tid * 4] = w1v;
      *(v4h*)&w2h[tid * 4] = w2v;
    }
  }

  // ---- finalize: P = E * u_i * v_j * (0.5*csinv_j + 0.5*rinv_i) ----
  __syncthreads();
  float* Pb = &P[((size_t)b * CN + i0 + wv * 16 + q * 4) * CN];
#pragma unroll
  for (int ct = 0; ct < 32; ++ct) {
    const float2 w = w12[ct * 16 + l];
    const float c1 = w.x;
    const float c2 = 0.5f * w.y;
#pragma unroll
    for (int g = 0; g < 4; ++g) {
      const float e = (float)eh[ct][g];
      Pb[(size_t)g * CN + ct * 16 + l] = e * fmaf(u_[g], c1, uri[g] * c2);
    }
  }
}

// ---------------------------------------------------------------------------
extern "C" void kernel_launch(void* const* d_in, const int* in_sizes, int n_in,
                              void* d_out, int out_size, void* d_ws, size_t ws_size,
                              hipStream_t stream) {
  const float* in_emb  = (const float*)d_in[0];
  const void*  mask    = d_in[1];
  const float* out_emb = (const float*)d_in[2];
  const float* pad     = (const float*)d_in[3];
  const float* pos     = (const float*)d_in[4];
  const float* W_a     = (const float*)d_in[5];
  const float* W_b     = (const float*)d_in[6];
  const float* w_aff   = (const float*)d_in[7];
  const float* b_aff   = (const float*)d_in[8];
  float* P = (float*)d_out;

  char* ws = (char*)d_ws;
  const size_t MB = 1024 * 1024;
  half_t* A_h  = (half_t*)ws;                              // 8 MB
  half_t* Bm_h = (half_t*)(ws + 8 * MB);                   // 8 MB
  int*    flag = (int*)(ws + 16 * MB);                     // 4 B
  half_t* WaF  = (half_t*)(ws + 16 * MB + 16384);          // 64 KB
  half_t* WbF  = (half_t*)(ws + 16 * MB + 16384 + 65536);  // 64 KB
  float* partInit = (float*)(ws + 16 * MB + 256 * 1024);   // 512 KB
  float* partIter = (float*)(ws + 16 * MB + 768 * 1024);   // 10 MB

  // dataflow slots: 10.5 MB contiguous starting at partInit, sentinel -1
  const int nclear4 = (512 * 1024 + 10 * 1024 * 1024) / 16;   // 688,128 float4
  const int nclrblk = (nclear4 + 511) / 512;                  // 1344

  k0_init<<<dim3(18 + nclrblk), dim3(512), 0, stream>>>(
      mask, flag, W_a, W_b, w_aff, WaF, WbF, (float4*)partInit, nclear4);
  prep_both<<<dim3(1024), dim3(256), 0, stream>>>(
      out_emb, pos, in_emb, pad, mask, flag, WaF, WbF, A_h, Bm_h);
  fused_reg<<<dim3(256), dim3(512), 0, stream>>>(
      A_h, Bm_h, b_aff, P, partInit, partIter);
}